// Round 3
// baseline (311.000 us; speedup 1.0000x reference)
//
#include <hip/hip_runtime.h>

typedef float  f32x2v __attribute__((ext_vector_type(2)));
typedef float  f32x16 __attribute__((ext_vector_type(16)));
typedef __bf16 bf16x8 __attribute__((ext_vector_type(8)));

constexpr int D_IN   = 128;   // NUM_SLICES * MAX_RANK
constexpr int KMAX   = 64;    // MAX_RANK
constexpr int N_OUT  = 4096;
constexpr int NSLICE = 2;

// Geometry experiment (single variable vs round 2's 305 us):
//   BM=32, BN=1024, 8 waves side-by-side, wave tile 32x128.
// Inner loop is register-identical to the proven 32x32x16 version
// (4 MFMA + 5 loads per k-step, acc = 4 x f32x16 = 64 VGPR).
// Point: each output row gets a 4 KB contiguous write per block
// (vs 512 B at BM=BN=128) -> DRAM page locality for the permuted scatter.
constexpr int BM = 32;
constexpr int BN = 1024;
constexpr int THREADS = 512;          // 8 waves, wn = wave id

// workspace layout (ws is ~1 GiB; we use ~9 MB)
constexpr size_t WBF_OFF = 0;         // bf16 W  [num_lora][N_OUT][KMAX]   (4 MB)
constexpr size_t XBF_OFF = 8u << 20;  // bf16 X  [logical_row][slice][KMAX] (4 MB)

__device__ __forceinline__ unsigned short f2bf(float f) {
    unsigned u = __builtin_bit_cast(unsigned, f);
    u += 0x7fffu + ((u >> 16) & 1u);   // RNE (inputs finite)
    return (unsigned short)(u >> 16);
}
__device__ __forceinline__ unsigned pk2(float a, float b) {
    return (unsigned)f2bf(a) | ((unsigned)f2bf(b) << 16);
}

// ---- pre-pass 1: W f32 -> bf16, same [n][k] layout -------------------------
__global__ __launch_bounds__(256)
void conv_w(const float* __restrict__ w, unsigned* __restrict__ wbf, int npairs) {
    int i = blockIdx.x * 256 + threadIdx.x;
    if (i >= npairs) return;
    f32x2v v = *(const f32x2v*)&w[(size_t)i * 2];
    wbf[i] = pk2(v.x, v.y);
}

// ---- pre-pass 2: X -> bf16 [logical_row][slice][KMAX], scaled/masked -------
__global__ __launch_bounds__(256)
void conv_x(const float* __restrict__ x,
            const int*   __restrict__ seg_indptr,
            const int*   __restrict__ weight_indices,
            const int*   __restrict__ lora_ranks,
            const float* __restrict__ scalings,
            const int*   __restrict__ permutation,
            unsigned* __restrict__ xbf,
            int num_segments, int m_tok)
{
    const int idx = blockIdx.x * 256 + threadIdx.x;          // m_tok*64 threads
    const int l   = idx >> 6;                                 // logical row
    if (l >= m_tok) return;
    const int c   = (idx & 63) * 2;                           // elem pair 0..126
    const int j   = c >> 6;                                   // slice
    const int k   = c & 63;

    int s = 0;
    for (int i = 0; i < num_segments; ++i)
        if (l >= seg_indptr[i] && l < seg_indptr[i + 1]) s = i;
    const int   w    = weight_indices[s];
    const int   r    = lora_ranks[w];
    const float scal = scalings[w];

    const int p = permutation[l];
    float v0 = 0.f, v1 = 0.f;
    if (k < r)     v0 = scal * x[(size_t)p * D_IN + j * r + k];
    if (k + 1 < r) v1 = scal * x[(size_t)p * D_IN + j * r + k + 1];
    xbf[idx] = pk2(v0, v1);
}

// ---- main: 32x32x16 fragments, 8 waves covering 32 rows x 1024 cols --------
// A/B frag layout: [m|n = lane&31][k = (lane>>5)*8 + e]; C layout (verified
// round 2): col = lane&31, row = (reg&3) + 8*(reg>>2) + 4*(lane>>5).
// Block-uniform segment (32 | 2048) and slice (1024 | 2048).
__global__ __launch_bounds__(THREADS, 4)
void lora_mfma(const __bf16* __restrict__ xbf,     // [l][slice][KMAX]
               const __bf16* __restrict__ wbf,     // [w][n][KMAX]
               const int*    __restrict__ seg_indptr,
               const int*    __restrict__ weight_indices,
               const int*    __restrict__ permutation,
               const int*    __restrict__ slice_offsets,
               float* __restrict__ out,
               int num_segments, int n_slices)
{
    __shared__ int Ps[BM];

    const int t    = threadIdx.x;
    const int row0 = blockIdx.y * BM;
    const int col0 = blockIdx.x * BN;

    if (t < BM) Ps[t] = permutation[row0 + t];
    __syncthreads();

    // adapter of this row-block's segment (block-uniform)
    int s = 0;
    for (int i = 0; i < num_segments; ++i)
        if (row0 >= seg_indptr[i] && row0 < seg_indptr[i + 1]) s = i;
    const int w = weight_indices[s];

    // slice of this col-block (block-uniform)
    int j = 0;
    for (int i = 1; i < n_slices; ++i) j += (col0 >= slice_offsets[i]);

    const int lane = t & 63;
    const int wv   = t >> 6;     // 0..7, col group (128 cols each)
    const int half = lane >> 5;  // k-half / row selector
    const int l32  = lane & 31;

    const int colw = col0 + wv * 128;

    const __bf16* __restrict__ Xb =
        xbf + ((size_t)(row0 + l32) * NSLICE + j) * KMAX + half * 8;
    const __bf16* __restrict__ Wb =
        wbf + ((size_t)w * N_OUT + colw + l32) * KMAX + half * 8;

    f32x16 acc[4] = {};

    #pragma unroll
    for (int ks = 0; ks < 4; ++ks) {              // k = ks*16 + half*8 + e
        const int kof = ks * 16;
        bf16x8 a = *(const bf16x8*)&Xb[kof];      // 32 X rows
        bf16x8 b0 = *(const bf16x8*)&Wb[kof];
        bf16x8 b1 = *(const bf16x8*)&Wb[(size_t)32 * KMAX + kof];
        bf16x8 b2 = *(const bf16x8*)&Wb[(size_t)64 * KMAX + kof];
        bf16x8 b3 = *(const bf16x8*)&Wb[(size_t)96 * KMAX + kof];
        acc[0] = __builtin_amdgcn_mfma_f32_32x32x16_bf16(a, b0, acc[0], 0, 0, 0);
        acc[1] = __builtin_amdgcn_mfma_f32_32x32x16_bf16(a, b1, acc[1], 0, 0, 0);
        acc[2] = __builtin_amdgcn_mfma_f32_32x32x16_bf16(a, b2, acc[2], 0, 0, 0);
        acc[3] = __builtin_amdgcn_mfma_f32_32x32x16_bf16(a, b3, acc[3], 0, 0, 0);
    }

    // epilogue: reg outer / nt inner -> per row, 4 consecutive full 128 B
    // lines from this wave; the 8 waves tile the row's 4 KB span.
    #pragma unroll
    for (int reg = 0; reg < 16; ++reg) {
        const int m = (reg & 3) + 8 * (reg >> 2) + 4 * half;
        float* op = &out[(size_t)Ps[m] * N_OUT + colw + l32];
        #pragma unroll
        for (int nt = 0; nt < 4; ++nt)
            op[nt * 32] = acc[nt][reg];
    }
}

extern "C" void kernel_launch(void* const* d_in, const int* in_sizes, int n_in,
                              void* d_out, int out_size, void* d_ws, size_t ws_size,
                              hipStream_t stream) {
    (void)n_in; (void)out_size; (void)ws_size;
    const float* x              = (const float*)d_in[0];
    const float* weights        = (const float*)d_in[1];
    const int*   seg_indptr     = (const int*)d_in[2];
    const int*   weight_indices = (const int*)d_in[3];
    const int*   lora_ranks     = (const int*)d_in[4];
    const float* scalings       = (const float*)d_in[5];
    const int*   permutation    = (const int*)d_in[6];
    const int*   slice_offsets  = (const int*)d_in[7];
    float*       out            = (float*)d_out;

    const int num_segments = in_sizes[2] - 1;
    const int n_slices     = in_sizes[7] - 1;
    const int m_tok        = in_sizes[6];           // permutation has M entries
    const int w_elems      = in_sizes[1];           // num_lora*N_OUT*KMAX

    unsigned* wbf = (unsigned*)((char*)d_ws + WBF_OFF);
    unsigned* xbf = (unsigned*)((char*)d_ws + XBF_OFF);

    const int wpairs = w_elems / 2;
    conv_w<<<(wpairs + 255) / 256, 256, 0, stream>>>(weights, wbf, wpairs);

    const int xthreads = m_tok * (NSLICE * KMAX / 2);
    conv_x<<<(xthreads + 255) / 256, 256, 0, stream>>>(
        x, seg_indptr, weight_indices, lora_ranks, scalings, permutation,
        xbf, num_segments, m_tok);

    dim3 grid(N_OUT / BN, m_tok / BM);
    lora_mfma<<<grid, THREADS, 0, stream>>>(
        (const __bf16*)xbf, (const __bf16*)wbf, seg_indptr, weight_indices,
        permutation, slice_offsets, out, num_segments, n_slices);
}